// Round 10
// baseline (1286.236 us; speedup 1.0000x reference)
//
#include <hip/hip_runtime.h>
#include <hip/hip_fp16.h>

// GCN: 3x (h = X@W; agg = CSR-gather(norm_e * h[src]) + norm_self*h + b; relu)
// then mean-pool by graph id and a 128x8 linear head.
// R1: scatter->gather. R3: fp16 payload. R8: fp16 B + NT stores.
// R2/R5/R6 falsified: MLP, locality-order, instr-count are not the limiter.
// R9: FETCH pinned at 8 XCD x 25.6 MB = whole-H16 per XCD (working set >> 4MB
//     per-XCD L2). Shard the FEATURE dim: sliced layout [f/16][node][16],
//     slice = 3.2 MB < 4 MB L2. Gather grid: slice = blockIdx&7 -> all blocks
//     of a slice land on one XCD (dispatch round-robin) -> h[src] reads become
//     L2 hits. Edge structure read with NT loads (no L2 pollution); w = dinv
//     on the fly. GEMM reads/writes the sliced layout.

#define THREADS 256
// sliced half layout: addr(node, f; M) = (f>>4)*(M*16) + node*16 + (f&15)

// ---------------- degree(int) / counts / dinv ----------------

__global__ __launch_bounds__(THREADS) void k_deg(const int* __restrict__ dst,
                                                 int* __restrict__ degi, int E) {
  int e = blockIdx.x * THREADS + threadIdx.x;
  if (e < E) atomicAdd(&degi[dst[e]], 1);
}

__global__ __launch_bounds__(THREADS) void k_cnt(const int* __restrict__ batch,
                                                 float* __restrict__ cnts, int N) {
  int i = blockIdx.x * THREADS + threadIdx.x;
  if (i < N) atomicAdd(&cnts[batch[i]], 1.0f);
}

__global__ __launch_bounds__(THREADS) void k_rsq(const int* __restrict__ degi,
                                                 float* __restrict__ dinv, int N) {
  int i = blockIdx.x * THREADS + threadIdx.x;
  if (i < N) dinv[i] = rsqrtf((float)degi[i] + 1.0f);
}

// ---------------- exclusive scan (3 kernels) ----------------

__global__ __launch_bounds__(THREADS) void k_scan1(const int* __restrict__ degi,
                                                   int* __restrict__ rowptr,
                                                   int* __restrict__ bsum, int N) {
  __shared__ int s[THREADS];
  int i = blockIdx.x * THREADS + threadIdx.x;
  int v = (i < N) ? degi[i] : 0;
  s[threadIdx.x] = v;
  __syncthreads();
#pragma unroll
  for (int off = 1; off < THREADS; off <<= 1) {
    int t = (threadIdx.x >= off) ? s[threadIdx.x - off] : 0;
    __syncthreads();
    s[threadIdx.x] += t;
    __syncthreads();
  }
  if (i < N) rowptr[i] = s[threadIdx.x] - v;  // exclusive
  if (threadIdx.x == THREADS - 1) bsum[blockIdx.x] = s[THREADS - 1];
}

__global__ __launch_bounds__(512) void k_scan2(int* __restrict__ bsum, int nb) {
  __shared__ int s[512];
  int v = (threadIdx.x < nb) ? bsum[threadIdx.x] : 0;
  s[threadIdx.x] = v;
  __syncthreads();
#pragma unroll
  for (int off = 1; off < 512; off <<= 1) {
    int t = (threadIdx.x >= off) ? s[threadIdx.x - off] : 0;
    __syncthreads();
    s[threadIdx.x] += t;
    __syncthreads();
  }
  if (threadIdx.x < nb) bsum[threadIdx.x] = s[threadIdx.x] - v;  // exclusive
}

__global__ __launch_bounds__(THREADS) void k_scan3(int* __restrict__ rowptr,
                                                   const int* __restrict__ bsum,
                                                   int N, int E) {
  int i = blockIdx.x * THREADS + threadIdx.x;
  if (i < N) rowptr[i] += bsum[blockIdx.x];
  if (i == 0) rowptr[N] = E;
}

// ---------------- CSR placement: src index by dst ----------------

__global__ __launch_bounds__(THREADS) void k_csr(const int* __restrict__ src,
                                                 const int* __restrict__ dst,
                                                 const int* __restrict__ rowptr,
                                                 int* __restrict__ cursor,
                                                 int* __restrict__ csrs, int E) {
  int e = blockIdx.x * THREADS + threadIdx.x;
  if (e >= E) return;
  int s = src[e];
  int d = dst[e];
  int pos = atomicAdd(&cursor[d], 1);
  csrs[rowptr[d] + pos] = s;
}

// ---------------- helpers ----------------

__device__ inline float4 h4_to_f4(float2 raw) {
  const __half2* h = (const __half2*)&raw;
  float2 a = __half22float2(h[0]);
  float2 b = __half22float2(h[1]);
  return make_float4(a.x, a.y, b.x, b.y);
}

// fp16 pack + non-temporal 8 B store
__device__ inline void st_nt_h4(__half* __restrict__ p, float x, float y,
                                float z, float w) {
  union {
    __half2 h2[2];
    unsigned long long u;
  } cv;
  cv.h2[0] = __floats2half2_rn(x, y);
  cv.h2[1] = __floats2half2_rn(z, w);
  __builtin_nontemporal_store(cv.u, (unsigned long long*)p);
}

// ---------------- GEMM: H16s[M,128] = fp16(X[M,128] @ W[128,128]), sliced out ----------------

template <int F32IN>
__global__ __launch_bounds__(THREADS) void k_gemm128(const float* __restrict__ Xf,
                                                     const __half* __restrict__ Xh,
                                                     const float* __restrict__ W,
                                                     __half* __restrict__ H16, int M) {
  __shared__ float4 sW[128 * 32];  // [k][colgroup] : W[k][c0..c0+3]
  const int t = threadIdx.x;
#pragma unroll
  for (int i = 0; i < 16; ++i) sW[t + i * 256] = ((const float4*)W)[t + i * 256];
  __syncthreads();

  const int tx = t & 31;
  const int ty = t >> 5;
  const int r0 = blockIdx.x * 64 + ty * 8;
  const size_t M16 = (size_t)M * 16;

  size_t r16[8];
#pragma unroll
  for (int i = 0; i < 8; ++i) {
    int r = r0 + i;
    if (r >= M) r = M - 1;  // clamp for safe (discarded) loads
    r16[i] = (size_t)r * 16;
  }

  float4 acc[8];
#pragma unroll
  for (int i = 0; i < 8; ++i) acc[i] = make_float4(0.f, 0.f, 0.f, 0.f);

#pragma unroll 2
  for (int k = 0; k < 128; k += 4) {
    float4 xv[8];
    if (F32IN) {
#pragma unroll
      for (int i = 0; i < 8; ++i)
        xv[i] = *(const float4*)(Xf + r16[i] * 8 + k);  // r*128 + k
    } else {
      const __half* base = Xh + (size_t)(k >> 4) * M16 + (k & 15);
#pragma unroll
      for (int i = 0; i < 8; ++i)
        xv[i] = h4_to_f4(*(const float2*)(base + r16[i]));
    }
#pragma unroll
    for (int kk = 0; kk < 4; ++kk) {
      float4 w = sW[(k + kk) * 32 + tx];
#pragma unroll
      for (int i = 0; i < 8; ++i) {
        float xs = (kk == 0) ? xv[i].x : (kk == 1) ? xv[i].y : (kk == 2) ? xv[i].z : xv[i].w;
        acc[i].x = fmaf(xs, w.x, acc[i].x);
        acc[i].y = fmaf(xs, w.y, acc[i].y);
        acc[i].z = fmaf(xs, w.z, acc[i].z);
        acc[i].w = fmaf(xs, w.w, acc[i].w);
      }
    }
  }

  // store: col c0 = tx*4 -> slice = tx>>2, f0 = (tx&3)*4
  __half* outb = H16 + (size_t)(tx >> 2) * M16 + (tx & 3) * 4;
#pragma unroll
  for (int i = 0; i < 8; ++i) {
    int r = r0 + i;
    if (r < M)
      st_nt_h4(outb + (size_t)r * 16, acc[i].x, acc[i].y, acc[i].z, acc[i].w);
  }
}

// ---------------- gather (sliced): per slice s, B16s[i] = sum w*H16s[src] + ... ----------------
// slice = blockIdx&7 -> XCD affinity; slice working set 3.2 MB fits 4 MB L2.
// 8 lanes per node (2 features per lane), 32 nodes per block.

__global__ __launch_bounds__(THREADS) void k_gather(const __half* __restrict__ H16,
                                                    const int* __restrict__ rowptr,
                                                    const int* __restrict__ csrs,
                                                    const float* __restrict__ dinv,
                                                    const float* __restrict__ bias,
                                                    __half* __restrict__ B16, int N,
                                                    int relu,
                                                    const int* __restrict__ batch,
                                                    float* __restrict__ pooled) {
  const int slice = blockIdx.x & 7;
  const int chunk = blockIdx.x >> 3;
  const int grp = threadIdx.x >> 3;   // 0..31
  const int lane = threadIdx.x & 7;   // 0..7
  const int i = chunk * 32 + grp;
  if (i >= N) return;

  const __half* Hs = H16 + (size_t)slice * ((size_t)N * 16);
  const int beg = __builtin_nontemporal_load(rowptr + i);
  const int end = __builtin_nontemporal_load(rowptr + i + 1);
  const float dd = dinv[i];
  const int l2 = lane * 2;

  float ax = 0.f, ay = 0.f;
  int k = beg;
  for (; k + 3 < end; k += 4) {
    int s0 = __builtin_nontemporal_load(csrs + k);
    int s1 = __builtin_nontemporal_load(csrs + k + 1);
    int s2 = __builtin_nontemporal_load(csrs + k + 2);
    int s3 = __builtin_nontemporal_load(csrs + k + 3);
    float w0 = dinv[s0] * dd, w1 = dinv[s1] * dd;
    float w2 = dinv[s2] * dd, w3 = dinv[s3] * dd;
    float2 h0 = __half22float2(*(const __half2*)(Hs + (size_t)s0 * 16 + l2));
    float2 h1 = __half22float2(*(const __half2*)(Hs + (size_t)s1 * 16 + l2));
    float2 h2 = __half22float2(*(const __half2*)(Hs + (size_t)s2 * 16 + l2));
    float2 h3 = __half22float2(*(const __half2*)(Hs + (size_t)s3 * 16 + l2));
    ax = fmaf(w0, h0.x, ax); ay = fmaf(w0, h0.y, ay);
    ax = fmaf(w1, h1.x, ax); ay = fmaf(w1, h1.y, ay);
    ax = fmaf(w2, h2.x, ax); ay = fmaf(w2, h2.y, ay);
    ax = fmaf(w3, h3.x, ax); ay = fmaf(w3, h3.y, ay);
  }
  for (; k < end; ++k) {
    int s0 = __builtin_nontemporal_load(csrs + k);
    float w0 = dinv[s0] * dd;
    float2 h0 = __half22float2(*(const __half2*)(Hs + (size_t)s0 * 16 + l2));
    ax = fmaf(w0, h0.x, ax); ay = fmaf(w0, h0.y, ay);
  }

  // self-loop + bias (+relu)
  float ns = dd * dd;
  float2 hs = __half22float2(*(const __half2*)(Hs + (size_t)i * 16 + l2));
  const int f = slice * 16 + l2;
  float vx = fmaf(hs.x, ns, ax) + bias[f];
  float vy = fmaf(hs.y, ns, ay) + bias[f + 1];
  if (relu) {
    vx = fmaxf(vx, 0.f);
    vy = fmaxf(vy, 0.f);
  }
  __half2 o = __floats2half2_rn(vx, vy);
  __builtin_nontemporal_store(*(unsigned int*)&o,
      (unsigned int*)(B16 + (size_t)slice * ((size_t)N * 16) + (size_t)i * 16 + l2));

  if (pooled) {
    int g = batch[i];
    atomicAdd(&pooled[(size_t)g * 128 + f], vx);
    atomicAdd(&pooled[(size_t)g * 128 + f + 1], vy);
  }
}

// ---------------- head ----------------

__global__ __launch_bounds__(THREADS) void k_head(const float* __restrict__ pooled,
                                                  const float* __restrict__ cnts,
                                                  const float* __restrict__ Wl,
                                                  const float* __restrict__ bl,
                                                  float* __restrict__ out, int G) {
  int gid = blockIdx.x * THREADS + threadIdx.x;
  int g = gid >> 3;
  int o = gid & 7;
  if (g >= G) return;
  float acc = 0.f;
#pragma unroll 8
  for (int k = 0; k < 128; ++k) acc = fmaf(pooled[(size_t)g * 128 + k], Wl[k * 8 + o], acc);
  out[g * 8 + o] = acc / fmaxf(cnts[g], 1.0f) + bl[o];
}

// ---------------- launch ----------------

extern "C" void kernel_launch(void* const* d_in, const int* in_sizes, int n_in,
                              void* d_out, int out_size, void* d_ws, size_t ws_size,
                              hipStream_t stream) {
  const float* x     = (const float*)d_in[0];
  const int*   ei    = (const int*)d_in[1];
  const int*   batch = (const int*)d_in[3];
  const float* W1 = (const float*)d_in[4];
  const float* b1 = (const float*)d_in[5];
  const float* W2 = (const float*)d_in[6];
  const float* b2 = (const float*)d_in[7];
  const float* W3 = (const float*)d_in[8];
  const float* b3 = (const float*)d_in[9];
  const float* Wl = (const float*)d_in[10];
  const float* bl = (const float*)d_in[11];
  float* out = (float*)d_out;

  const int N = in_sizes[0] / 128;
  const int E = in_sizes[1] / 2;
  const int G = out_size / 8;
  const int* srcp = ei;
  const int* dstp = ei + E;

  char* ws = (char*)d_ws;
  __half* H16 = (__half*)ws;                       // [8][N][16] sliced fp16
  __half* B16 = H16 + (size_t)N * 128;             // [8][N][16] sliced fp16
  // zeroed region: degi, cursor, cnts, pooled (contiguous)
  int*   degi   = (int*)(B16 + (size_t)N * 128);   // N
  int*   cursor = degi + N;                        // N
  float* cnts   = (float*)(cursor + N);            // G
  float* pooled = cnts + G;                        // G*128
  // non-zeroed scratch
  float* dinv    = pooled + (size_t)G * 128;       // N
  int*   rowptr  = (int*)(dinv + N);               // N+1
  int*   bsum    = rowptr + N + 1;                 // scan partials (<=2048)
  int*   csrs    = bsum + 2048;                    // E src indices

  const size_t zero_bytes = ((size_t)2 * N + G + (size_t)G * 128) * sizeof(float);
  hipMemsetAsync(degi, 0, zero_bytes, stream);

  const int nbE = (E + THREADS - 1) / THREADS;
  const int nbN = (N + THREADS - 1) / THREADS;

  // ---- CSR build (once per call, reused by all 3 layers) ----
  k_deg<<<nbE, THREADS, 0, stream>>>(dstp, degi, E);
  k_cnt<<<nbN, THREADS, 0, stream>>>(batch, cnts, N);
  k_rsq<<<nbN, THREADS, 0, stream>>>(degi, dinv, N);
  k_scan1<<<nbN, THREADS, 0, stream>>>(degi, rowptr, bsum, N);
  k_scan2<<<1, 512, 0, stream>>>(bsum, nbN);
  k_scan3<<<nbN, THREADS, 0, stream>>>(rowptr, bsum, N, E);
  k_csr<<<nbE, THREADS, 0, stream>>>(srcp, dstp, rowptr, cursor, csrs, E);

  const int gemm_blocks = (N + 63) / 64;
  const int gat_blocks = 8 * ((N + 31) / 32);

  // ---- layer 1 ----
  k_gemm128<1><<<gemm_blocks, THREADS, 0, stream>>>(x, nullptr, W1, H16, N);
  k_gather<<<gat_blocks, THREADS, 0, stream>>>(H16, rowptr, csrs, dinv, b1, B16, N, 1,
                                               nullptr, nullptr);
  // ---- layer 2 ----
  k_gemm128<0><<<gemm_blocks, THREADS, 0, stream>>>(nullptr, B16, W2, H16, N);
  k_gather<<<gat_blocks, THREADS, 0, stream>>>(H16, rowptr, csrs, dinv, b2, B16, N, 1,
                                               nullptr, nullptr);
  // ---- layer 3 (no relu, fused mean-pool accumulation) ----
  k_gemm128<0><<<gemm_blocks, THREADS, 0, stream>>>(nullptr, B16, W3, H16, N);
  k_gather<<<gat_blocks, THREADS, 0, stream>>>(H16, rowptr, csrs, dinv, b3, B16, N, 0,
                                               batch, pooled);

  // ---- head ----
  k_head<<<(G * 8 + THREADS - 1) / THREADS, THREADS, 0, stream>>>(pooled, cnts, Wl, bl, out, G);
}

// Round 12
// 1092.608 us; speedup vs baseline: 1.1772x; 1.1772x over previous
//
#include <hip/hip_runtime.h>
#include <hip/hip_fp16.h>

// GCN: 3x (h = X@W; agg = CSR-gather(norm_e * h[src]) + norm_self*h + b; relu)
// then mean-pool by graph id and a 128x8 linear head.
// R1: scatter->gather. R3: fp16 payload. R8: fp16 B + NT stores (817 us).
// R9 (reverted): feature-sliced L2-resident gather halved FETCH (192->90 MB)
//     but 1.5x slower -> gather is L2 REQUEST-throughput bound (~30 req/ns
//     constant across R1/R3/R9), not byte/locality bound.
// R6 retro-diagnosis: its 16-lane loads were fine; the 2x regression was the
//     strided partial-line fp32 store (WRITE 450 MB, RMW).
// R10: fewest requests at full line utilization: 16 lanes/edge x 16 B loads
//     (4 full lines/edge, half the load instrs of R8) + contiguous 16 B/lane
//     NT fp16 store (256 B full-line coverage, no partial lines).
// R11: fix compile — __builtin_nontemporal_store needs a native vector type,
//     use ext_vector_type(4) float instead of HIP float4.

#define THREADS 256

typedef float fvec4 __attribute__((ext_vector_type(4)));

// ---------------- degree(int) / counts / dinv ----------------

__global__ __launch_bounds__(THREADS) void k_deg(const int* __restrict__ dst,
                                                 int* __restrict__ degi, int E) {
  int e = blockIdx.x * THREADS + threadIdx.x;
  if (e < E) atomicAdd(&degi[dst[e]], 1);
}

__global__ __launch_bounds__(THREADS) void k_cnt(const int* __restrict__ batch,
                                                 float* __restrict__ cnts, int N) {
  int i = blockIdx.x * THREADS + threadIdx.x;
  if (i < N) atomicAdd(&cnts[batch[i]], 1.0f);
}

__global__ __launch_bounds__(THREADS) void k_rsq(const int* __restrict__ degi,
                                                 float* __restrict__ dinv, int N) {
  int i = blockIdx.x * THREADS + threadIdx.x;
  if (i < N) dinv[i] = rsqrtf((float)degi[i] + 1.0f);
}

// ---------------- exclusive scan (3 kernels) ----------------

__global__ __launch_bounds__(THREADS) void k_scan1(const int* __restrict__ degi,
                                                   int* __restrict__ rowptr,
                                                   int* __restrict__ bsum, int N) {
  __shared__ int s[THREADS];
  int i = blockIdx.x * THREADS + threadIdx.x;
  int v = (i < N) ? degi[i] : 0;
  s[threadIdx.x] = v;
  __syncthreads();
#pragma unroll
  for (int off = 1; off < THREADS; off <<= 1) {
    int t = (threadIdx.x >= off) ? s[threadIdx.x - off] : 0;
    __syncthreads();
    s[threadIdx.x] += t;
    __syncthreads();
  }
  if (i < N) rowptr[i] = s[threadIdx.x] - v;  // exclusive
  if (threadIdx.x == THREADS - 1) bsum[blockIdx.x] = s[THREADS - 1];
}

__global__ __launch_bounds__(512) void k_scan2(int* __restrict__ bsum, int nb) {
  __shared__ int s[512];
  int v = (threadIdx.x < nb) ? bsum[threadIdx.x] : 0;
  s[threadIdx.x] = v;
  __syncthreads();
#pragma unroll
  for (int off = 1; off < 512; off <<= 1) {
    int t = (threadIdx.x >= off) ? s[threadIdx.x - off] : 0;
    __syncthreads();
    s[threadIdx.x] += t;
    __syncthreads();
  }
  if (threadIdx.x < nb) bsum[threadIdx.x] = s[threadIdx.x] - v;  // exclusive
}

__global__ __launch_bounds__(THREADS) void k_scan3(int* __restrict__ rowptr,
                                                   const int* __restrict__ bsum,
                                                   int N, int E) {
  int i = blockIdx.x * THREADS + threadIdx.x;
  if (i < N) rowptr[i] += bsum[blockIdx.x];
  if (i == 0) rowptr[N] = E;
}

// ---------------- CSR placement: packed {src, w} records by dst ----------------

__global__ __launch_bounds__(THREADS) void k_csr(const int* __restrict__ src,
                                                 const int* __restrict__ dst,
                                                 const int* __restrict__ rowptr,
                                                 int* __restrict__ cursor,
                                                 const float* __restrict__ dinv,
                                                 int2* __restrict__ rec, int E) {
  int e = blockIdx.x * THREADS + threadIdx.x;
  if (e >= E) return;
  int s = src[e];
  int d = dst[e];
  int pos = atomicAdd(&cursor[d], 1);
  int idx = rowptr[d] + pos;
  float w = dinv[s] * dinv[d];
  rec[idx] = make_int2(s, __float_as_int(w));
}

// ---------------- loaders / stores ----------------

__device__ inline float4 ldrow4(const float* __restrict__ p) {
  return *(const float4*)p;
}

__device__ inline float4 ldrow4(const __half* __restrict__ p) {
  float2 raw = *(const float2*)p;  // 4 halves
  const __half2* h = (const __half2*)&raw;
  float2 a = __half22float2(h[0]);
  float2 b = __half22float2(h[1]);
  return make_float4(a.x, a.y, b.x, b.y);
}

struct f8 { float v[8]; };

__device__ inline f8 ld_h8(const __half* __restrict__ p) {
  float4 raw = *(const float4*)p;  // 8 halves, 16 B
  const __half2* h = (const __half2*)&raw;
  float2 a = __half22float2(h[0]);
  float2 b = __half22float2(h[1]);
  float2 c = __half22float2(h[2]);
  float2 d = __half22float2(h[3]);
  f8 o;
  o.v[0] = a.x; o.v[1] = a.y; o.v[2] = b.x; o.v[3] = b.y;
  o.v[4] = c.x; o.v[5] = c.y; o.v[6] = d.x; o.v[7] = d.y;
  return o;
}

// fp16 pack + non-temporal 8 B store
__device__ inline void st_nt_h4(__half* __restrict__ p, float x, float y,
                                float z, float w) {
  union {
    __half2 h2[2];
    unsigned long long u;
  } cv;
  cv.h2[0] = __floats2half2_rn(x, y);
  cv.h2[1] = __floats2half2_rn(z, w);
  __builtin_nontemporal_store(cv.u, (unsigned long long*)p);
}

// fp16 pack + non-temporal 16 B store (8 halves, contiguous)
__device__ inline void st_nt_h8(__half* __restrict__ p, const float* v) {
  union {
    __half2 h2[4];
    fvec4 f;
  } cv;
  cv.h2[0] = __floats2half2_rn(v[0], v[1]);
  cv.h2[1] = __floats2half2_rn(v[2], v[3]);
  cv.h2[2] = __floats2half2_rn(v[4], v[5]);
  cv.h2[3] = __floats2half2_rn(v[6], v[7]);
  __builtin_nontemporal_store(cv.f, (fvec4*)p);
}

// ---------------- GEMM: H16[M,128] = fp16(X[M,128] @ W[128,128]) ----------------

template <typename T>
__global__ __launch_bounds__(THREADS) void k_gemm128(const T* __restrict__ X,
                                                     const float* __restrict__ W,
                                                     __half* __restrict__ H16, int M) {
  __shared__ float4 sW[128 * 32];  // [k][colgroup] : W[k][c0..c0+3]
  const int t = threadIdx.x;
#pragma unroll
  for (int i = 0; i < 16; ++i) sW[t + i * 256] = ((const float4*)W)[t + i * 256];
  __syncthreads();

  const int tx = t & 31;
  const int ty = t >> 5;
  const int r0 = blockIdx.x * 64 + ty * 8;

  const T* xp[8];
#pragma unroll
  for (int i = 0; i < 8; ++i) {
    int r = r0 + i;
    if (r >= M) r = M - 1;
    xp[i] = X + (size_t)r * 128;
  }

  float4 acc[8];
#pragma unroll
  for (int i = 0; i < 8; ++i) acc[i] = make_float4(0.f, 0.f, 0.f, 0.f);

#pragma unroll 2
  for (int k = 0; k < 128; k += 4) {
    float4 xv[8];
#pragma unroll
    for (int i = 0; i < 8; ++i) xv[i] = ldrow4(xp[i] + k);
#pragma unroll
    for (int kk = 0; kk < 4; ++kk) {
      float4 w = sW[(k + kk) * 32 + tx];
#pragma unroll
      for (int i = 0; i < 8; ++i) {
        float xs = (kk == 0) ? xv[i].x : (kk == 1) ? xv[i].y : (kk == 2) ? xv[i].z : xv[i].w;
        acc[i].x = fmaf(xs, w.x, acc[i].x);
        acc[i].y = fmaf(xs, w.y, acc[i].y);
        acc[i].z = fmaf(xs, w.z, acc[i].z);
        acc[i].w = fmaf(xs, w.w, acc[i].w);
      }
    }
  }

#pragma unroll
  for (int i = 0; i < 8; ++i) {
    int r = r0 + i;
    if (r < M)
      st_nt_h4(H16 + (size_t)r * 128 + tx * 4, acc[i].x, acc[i].y, acc[i].z, acc[i].w);
  }
}

// ---------------- gather: B16[i] = fp16(sum_in w*H16[src] + dinv_i^2*H16[i] + bias) ----------------
// 16 lanes per dst node, 16 B (8 halves) per lane: 4 full lines/edge, half the
// load instructions of the 32-lane form. Contiguous 16 B/lane NT store.

__global__ __launch_bounds__(THREADS) void k_gather(const __half* __restrict__ H16,
                                                    const int* __restrict__ rowptr,
                                                    const int2* __restrict__ rec,
                                                    const float* __restrict__ dinv,
                                                    const float* __restrict__ bias,
                                                    __half* __restrict__ B16, int N,
                                                    int relu,
                                                    const int* __restrict__ batch,
                                                    float* __restrict__ pooled) {
  int gid = blockIdx.x * THREADS + threadIdx.x;
  int i = gid >> 4;
  int lane = gid & 15;
  if (i >= N) return;
  int beg = rowptr[i];
  int end = rowptr[i + 1];
  const int co = lane * 8;  // this lane's 8-column slice

  float acc[8];
#pragma unroll
  for (int u = 0; u < 8; ++u) acc[u] = 0.f;

  int k = beg;
  for (; k + 3 < end; k += 4) {
    int2 r0 = rec[k],     r1 = rec[k + 1];
    int2 r2 = rec[k + 2], r3 = rec[k + 3];
    f8 h0 = ld_h8(H16 + (size_t)r0.x * 128 + co);
    f8 h1 = ld_h8(H16 + (size_t)r1.x * 128 + co);
    f8 h2 = ld_h8(H16 + (size_t)r2.x * 128 + co);
    f8 h3 = ld_h8(H16 + (size_t)r3.x * 128 + co);
    float w0 = __int_as_float(r0.y), w1 = __int_as_float(r1.y);
    float w2 = __int_as_float(r2.y), w3 = __int_as_float(r3.y);
#pragma unroll
    for (int u = 0; u < 8; ++u) {
      acc[u] = fmaf(w0, h0.v[u], acc[u]);
      acc[u] = fmaf(w1, h1.v[u], acc[u]);
      acc[u] = fmaf(w2, h2.v[u], acc[u]);
      acc[u] = fmaf(w3, h3.v[u], acc[u]);
    }
  }
  for (; k < end; ++k) {
    int2 r0 = rec[k];
    float w0 = __int_as_float(r0.y);
    f8 h0 = ld_h8(H16 + (size_t)r0.x * 128 + co);
#pragma unroll
    for (int u = 0; u < 8; ++u) acc[u] = fmaf(w0, h0.v[u], acc[u]);
  }

  float di = dinv[i];
  float ns = di * di;
  f8 hs = ld_h8(H16 + (size_t)i * 128 + co);
  float4 bb0 = *(const float4*)(bias + co);
  float4 bb1 = *(const float4*)(bias + co + 4);
  float v[8];
  v[0] = fmaf(hs.v[0], ns, acc[0]) + bb0.x;
  v[1] = fmaf(hs.v[1], ns, acc[1]) + bb0.y;
  v[2] = fmaf(hs.v[2], ns, acc[2]) + bb0.z;
  v[3] = fmaf(hs.v[3], ns, acc[3]) + bb0.w;
  v[4] = fmaf(hs.v[4], ns, acc[4]) + bb1.x;
  v[5] = fmaf(hs.v[5], ns, acc[5]) + bb1.y;
  v[6] = fmaf(hs.v[6], ns, acc[6]) + bb1.z;
  v[7] = fmaf(hs.v[7], ns, acc[7]) + bb1.w;
  if (relu) {
#pragma unroll
    for (int u = 0; u < 8; ++u) v[u] = fmaxf(v[u], 0.f);
  }
  st_nt_h8(B16 + (size_t)i * 128 + co, v);  // 16 B contiguous per lane

  if (pooled) {
    int g = batch[i];
    float* o = pooled + (size_t)g * 128 + co;
#pragma unroll
    for (int u = 0; u < 8; ++u) atomicAdd(o + u, v[u]);
  }
}

// ---------------- head ----------------

__global__ __launch_bounds__(THREADS) void k_head(const float* __restrict__ pooled,
                                                  const float* __restrict__ cnts,
                                                  const float* __restrict__ Wl,
                                                  const float* __restrict__ bl,
                                                  float* __restrict__ out, int G) {
  int gid = blockIdx.x * THREADS + threadIdx.x;
  int g = gid >> 3;
  int o = gid & 7;
  if (g >= G) return;
  float acc = 0.f;
#pragma unroll 8
  for (int k = 0; k < 128; ++k) acc = fmaf(pooled[(size_t)g * 128 + k], Wl[k * 8 + o], acc);
  out[g * 8 + o] = acc / fmaxf(cnts[g], 1.0f) + bl[o];
}

// ---------------- launch ----------------

extern "C" void kernel_launch(void* const* d_in, const int* in_sizes, int n_in,
                              void* d_out, int out_size, void* d_ws, size_t ws_size,
                              hipStream_t stream) {
  const float* x     = (const float*)d_in[0];
  const int*   ei    = (const int*)d_in[1];
  const int*   batch = (const int*)d_in[3];
  const float* W1 = (const float*)d_in[4];
  const float* b1 = (const float*)d_in[5];
  const float* W2 = (const float*)d_in[6];
  const float* b2 = (const float*)d_in[7];
  const float* W3 = (const float*)d_in[8];
  const float* b3 = (const float*)d_in[9];
  const float* Wl = (const float*)d_in[10];
  const float* bl = (const float*)d_in[11];
  float* out = (float*)d_out;

  const int N = in_sizes[0] / 128;
  const int E = in_sizes[1] / 2;
  const int G = out_size / 8;
  const int* srcp = ei;
  const int* dstp = ei + E;

  char* ws = (char*)d_ws;
  __half* H16 = (__half*)ws;                       // [N,128] fp16 GEMM output
  __half* B16 = H16 + (size_t)N * 128;             // [N,128] fp16 activations
  // zeroed region: degi, cursor, cnts, pooled (contiguous)
  int*   degi   = (int*)(B16 + (size_t)N * 128);   // N
  int*   cursor = degi + N;                        // N
  float* cnts   = (float*)(cursor + N);            // G
  float* pooled = cnts + G;                        // G*128
  // non-zeroed scratch
  float* dinv    = pooled + (size_t)G * 128;       // N
  int*   rowptr  = (int*)(dinv + N);               // N+1
  int*   bsum    = rowptr + N + 1;                 // scan partials (<=2048)
  int2*  rec     = (int2*)(bsum + 2048);           // E packed records

  const size_t zero_bytes = ((size_t)2 * N + G + (size_t)G * 128) * sizeof(float);
  (void)hipMemsetAsync(degi, 0, zero_bytes, stream);

  const int nbE = (E + THREADS - 1) / THREADS;
  const int nbN = (N + THREADS - 1) / THREADS;

  // ---- CSR build (once per call, reused by all 3 layers) ----
  k_deg<<<nbE, THREADS, 0, stream>>>(dstp, degi, E);
  k_cnt<<<nbN, THREADS, 0, stream>>>(batch, cnts, N);
  k_rsq<<<nbN, THREADS, 0, stream>>>(degi, dinv, N);
  k_scan1<<<nbN, THREADS, 0, stream>>>(degi, rowptr, bsum, N);
  k_scan2<<<1, 512, 0, stream>>>(bsum, nbN);
  k_scan3<<<nbN, THREADS, 0, stream>>>(rowptr, bsum, N, E);
  k_csr<<<nbE, THREADS, 0, stream>>>(srcp, dstp, rowptr, cursor, dinv, rec, E);

  const int gemm_blocks = (N + 63) / 64;
  const int gat_blocks = (int)(((long long)N * 16 + THREADS - 1) / THREADS);

  // ---- layer 1 ----
  k_gemm128<float><<<gemm_blocks, THREADS, 0, stream>>>(x, W1, H16, N);
  k_gather<<<gat_blocks, THREADS, 0, stream>>>(H16, rowptr, rec, dinv, b1, B16, N, 1,
                                               nullptr, nullptr);
  // ---- layer 2 ----
  k_gemm128<__half><<<gemm_blocks, THREADS, 0, stream>>>(B16, W2, H16, N);
  k_gather<<<gat_blocks, THREADS, 0, stream>>>(H16, rowptr, rec, dinv, b2, B16, N, 1,
                                               nullptr, nullptr);
  // ---- layer 3 (no relu, fused mean-pool accumulation) ----
  k_gemm128<__half><<<gemm_blocks, THREADS, 0, stream>>>(B16, W3, H16, N);
  k_gather<<<gat_blocks, THREADS, 0, stream>>>(H16, rowptr, rec, dinv, b3, B16, N, 0,
                                               batch, pooled);

  // ---- head ----
  k_head<<<(G * 8 + THREADS - 1) / THREADS, THREADS, 0, stream>>>(pooled, cnts, Wl, bl, out, G);
}

// Round 13
// 704.658 us; speedup vs baseline: 1.8253x; 1.5506x over previous
//
#include <hip/hip_runtime.h>
#include <hip/hip_fp16.h>

// GCN: 3x (h = X@W; agg = CSR-gather(norm_e * h[src]) + norm_self*h + b; relu)
// then mean-pool by graph id and a 128x8 linear head.
// R1: scatter->gather. R3: fp16 payload. R8: fp16 B + NT stores (817 us, best).
// R2/R5/R6/R9/R10-11 falsified: MLP, bucketing, instr-count, L2-slicing, and
//     16-lane shapes all regress. 32-lane x 8B gather = local optimum.
// R12: algebraic — everything after the last relu is linear:
//     out = mean_pool(A*(B2 @ (W3@Wlin))) + b3@Wlin + blin.
//     Fold Wc=W3@Wlin on device; P3 = B2@Wc is [N,8] fp32 (3.2 MB, L2-fit);
//     layer-3 gather reads 16 B/edge (was 256 B) and pools directly.

#define THREADS 256

// ---------------- degree(int) / counts / dinv ----------------

__global__ __launch_bounds__(THREADS) void k_deg(const int* __restrict__ dst,
                                                 int* __restrict__ degi, int E) {
  int e = blockIdx.x * THREADS + threadIdx.x;
  if (e < E) atomicAdd(&degi[dst[e]], 1);
}

__global__ __launch_bounds__(THREADS) void k_cnt(const int* __restrict__ batch,
                                                 float* __restrict__ cnts, int N) {
  int i = blockIdx.x * THREADS + threadIdx.x;
  if (i < N) atomicAdd(&cnts[batch[i]], 1.0f);
}

__global__ __launch_bounds__(THREADS) void k_rsq(const int* __restrict__ degi,
                                                 float* __restrict__ dinv, int N) {
  int i = blockIdx.x * THREADS + threadIdx.x;
  if (i < N) dinv[i] = rsqrtf((float)degi[i] + 1.0f);
}

// ---------------- exclusive scan (3 kernels) ----------------

__global__ __launch_bounds__(THREADS) void k_scan1(const int* __restrict__ degi,
                                                   int* __restrict__ rowptr,
                                                   int* __restrict__ bsum, int N) {
  __shared__ int s[THREADS];
  int i = blockIdx.x * THREADS + threadIdx.x;
  int v = (i < N) ? degi[i] : 0;
  s[threadIdx.x] = v;
  __syncthreads();
#pragma unroll
  for (int off = 1; off < THREADS; off <<= 1) {
    int t = (threadIdx.x >= off) ? s[threadIdx.x - off] : 0;
    __syncthreads();
    s[threadIdx.x] += t;
    __syncthreads();
  }
  if (i < N) rowptr[i] = s[threadIdx.x] - v;  // exclusive
  if (threadIdx.x == THREADS - 1) bsum[blockIdx.x] = s[THREADS - 1];
}

__global__ __launch_bounds__(512) void k_scan2(int* __restrict__ bsum, int nb) {
  __shared__ int s[512];
  int v = (threadIdx.x < nb) ? bsum[threadIdx.x] : 0;
  s[threadIdx.x] = v;
  __syncthreads();
#pragma unroll
  for (int off = 1; off < 512; off <<= 1) {
    int t = (threadIdx.x >= off) ? s[threadIdx.x - off] : 0;
    __syncthreads();
    s[threadIdx.x] += t;
    __syncthreads();
  }
  if (threadIdx.x < nb) bsum[threadIdx.x] = s[threadIdx.x] - v;  // exclusive
}

__global__ __launch_bounds__(THREADS) void k_scan3(int* __restrict__ rowptr,
                                                   const int* __restrict__ bsum,
                                                   int N, int E) {
  int i = blockIdx.x * THREADS + threadIdx.x;
  if (i < N) rowptr[i] += bsum[blockIdx.x];
  if (i == 0) rowptr[N] = E;
}

// ---------------- CSR placement: packed {src, w} records by dst ----------------

__global__ __launch_bounds__(THREADS) void k_csr(const int* __restrict__ src,
                                                 const int* __restrict__ dst,
                                                 const int* __restrict__ rowptr,
                                                 int* __restrict__ cursor,
                                                 const float* __restrict__ dinv,
                                                 int2* __restrict__ rec, int E) {
  int e = blockIdx.x * THREADS + threadIdx.x;
  if (e >= E) return;
  int s = src[e];
  int d = dst[e];
  int pos = atomicAdd(&cursor[d], 1);
  int idx = rowptr[d] + pos;
  float w = dinv[s] * dinv[d];
  rec[idx] = make_int2(s, __float_as_int(w));
}

// ---------------- combined tail weights: Wc = W3@Wlin, bc = b3@Wlin + blin ----------------

__global__ __launch_bounds__(THREADS) void k_wcomb(const float* __restrict__ W3,
                                                   const float* __restrict__ Wl,
                                                   const float* __restrict__ b3,
                                                   const float* __restrict__ bl,
                                                   float* __restrict__ Wc,
                                                   float* __restrict__ bc) {
  int idx = blockIdx.x * THREADS + threadIdx.x;
  if (idx < 1024) {
    int k = idx >> 3, o = idx & 7;
    float a = 0.f;
#pragma unroll 8
    for (int j = 0; j < 128; ++j) a = fmaf(W3[k * 128 + j], Wl[j * 8 + o], a);
    Wc[idx] = a;
  }
  if (idx < 8) {
    float a = bl[idx];
    for (int j = 0; j < 128; ++j) a = fmaf(b3[j], Wl[j * 8 + idx], a);
    bc[idx] = a;
  }
}

// ---------------- loaders / stores ----------------

__device__ inline float4 ldrow4(const float* __restrict__ p) {
  return *(const float4*)p;
}

__device__ inline float4 ldrow4(const __half* __restrict__ p) {
  float2 raw = *(const float2*)p;  // 4 halves
  const __half2* h = (const __half2*)&raw;
  float2 a = __half22float2(h[0]);
  float2 b = __half22float2(h[1]);
  return make_float4(a.x, a.y, b.x, b.y);
}

struct f8 { float v[8]; };

__device__ inline f8 ld_h8(const __half* __restrict__ p) {
  float4 raw = *(const float4*)p;  // 8 halves, 16 B
  const __half2* h = (const __half2*)&raw;
  float2 a = __half22float2(h[0]);
  float2 b = __half22float2(h[1]);
  float2 c = __half22float2(h[2]);
  float2 d = __half22float2(h[3]);
  f8 o;
  o.v[0] = a.x; o.v[1] = a.y; o.v[2] = b.x; o.v[3] = b.y;
  o.v[4] = c.x; o.v[5] = c.y; o.v[6] = d.x; o.v[7] = d.y;
  return o;
}

// fp16 pack + non-temporal 8 B store
__device__ inline void st_nt_h4(__half* __restrict__ p, float x, float y,
                                float z, float w) {
  union {
    __half2 h2[2];
    unsigned long long u;
  } cv;
  cv.h2[0] = __floats2half2_rn(x, y);
  cv.h2[1] = __floats2half2_rn(z, w);
  __builtin_nontemporal_store(cv.u, (unsigned long long*)p);
}

// ---------------- GEMM: H16[M,128] = fp16(X[M,128] @ W[128,128]) ----------------

template <typename T>
__global__ __launch_bounds__(THREADS) void k_gemm128(const T* __restrict__ X,
                                                     const float* __restrict__ W,
                                                     __half* __restrict__ H16, int M) {
  __shared__ float4 sW[128 * 32];  // [k][colgroup] : W[k][c0..c0+3]
  const int t = threadIdx.x;
#pragma unroll
  for (int i = 0; i < 16; ++i) sW[t + i * 256] = ((const float4*)W)[t + i * 256];
  __syncthreads();

  const int tx = t & 31;
  const int ty = t >> 5;
  const int r0 = blockIdx.x * 64 + ty * 8;

  const T* xp[8];
#pragma unroll
  for (int i = 0; i < 8; ++i) {
    int r = r0 + i;
    if (r >= M) r = M - 1;
    xp[i] = X + (size_t)r * 128;
  }

  float4 acc[8];
#pragma unroll
  for (int i = 0; i < 8; ++i) acc[i] = make_float4(0.f, 0.f, 0.f, 0.f);

#pragma unroll 2
  for (int k = 0; k < 128; k += 4) {
    float4 xv[8];
#pragma unroll
    for (int i = 0; i < 8; ++i) xv[i] = ldrow4(xp[i] + k);
#pragma unroll
    for (int kk = 0; kk < 4; ++kk) {
      float4 w = sW[(k + kk) * 32 + tx];
#pragma unroll
      for (int i = 0; i < 8; ++i) {
        float xs = (kk == 0) ? xv[i].x : (kk == 1) ? xv[i].y : (kk == 2) ? xv[i].z : xv[i].w;
        acc[i].x = fmaf(xs, w.x, acc[i].x);
        acc[i].y = fmaf(xs, w.y, acc[i].y);
        acc[i].z = fmaf(xs, w.z, acc[i].z);
        acc[i].w = fmaf(xs, w.w, acc[i].w);
      }
    }
  }

#pragma unroll
  for (int i = 0; i < 8; ++i) {
    int r = r0 + i;
    if (r < M)
      st_nt_h4(H16 + (size_t)r * 128 + tx * 4, acc[i].x, acc[i].y, acc[i].z, acc[i].w);
  }
}

// ---------------- small GEMM: P3[M,8] = fp32(B16[M,128] @ Wc[128,8]) ----------------
// One thread per row; Wc staged in LDS (4 KB, broadcast reads).

__global__ __launch_bounds__(THREADS) void k_gemm8(const __half* __restrict__ B16,
                                                   const float* __restrict__ Wc,
                                                   float* __restrict__ P3, int M) {
  __shared__ float sWc[1024];
#pragma unroll
  for (int i = 0; i < 4; ++i) sWc[threadIdx.x + i * 256] = Wc[threadIdx.x + i * 256];
  __syncthreads();

  int i = blockIdx.x * THREADS + threadIdx.x;
  if (i >= M) return;

  float acc[8];
#pragma unroll
  for (int o = 0; o < 8; ++o) acc[o] = 0.f;

  const __half* row = B16 + (size_t)i * 128;
#pragma unroll 4
  for (int k = 0; k < 128; k += 8) {
    f8 x = ld_h8(row + k);
#pragma unroll
    for (int u = 0; u < 8; ++u) {
      const float* wr = &sWc[(k + u) * 8];
#pragma unroll
      for (int o = 0; o < 8; ++o) acc[o] = fmaf(x.v[u], wr[o], acc[o]);
    }
  }
  float4* out = (float4*)(P3 + (size_t)i * 8);
  out[0] = make_float4(acc[0], acc[1], acc[2], acc[3]);
  out[1] = make_float4(acc[4], acc[5], acc[6], acc[7]);
}

// ---------------- gather: B16[i] = fp16(sum_in w*H16[src] + dinv_i^2*H16[i] + bias) ----------------
// R8 proven shape: 32 lanes per dst node, 8 B per lane; unroll 4; NT store.

__global__ __launch_bounds__(THREADS) void k_gather(const __half* __restrict__ H16,
                                                    const int* __restrict__ rowptr,
                                                    const int2* __restrict__ rec,
                                                    const float* __restrict__ dinv,
                                                    const float* __restrict__ bias,
                                                    __half* __restrict__ B16, int N) {
  int gid = blockIdx.x * THREADS + threadIdx.x;
  int i = gid >> 5;
  int lane = gid & 31;
  if (i >= N) return;
  int beg = rowptr[i];
  int end = rowptr[i + 1];

  float4 acc = make_float4(0.f, 0.f, 0.f, 0.f);
  int k = beg;
  for (; k + 3 < end; k += 4) {
    int2 r0 = rec[k],     r1 = rec[k + 1];
    int2 r2 = rec[k + 2], r3 = rec[k + 3];
    float4 h0 = ldrow4(H16 + (size_t)r0.x * 128 + lane * 4);
    float4 h1 = ldrow4(H16 + (size_t)r1.x * 128 + lane * 4);
    float4 h2 = ldrow4(H16 + (size_t)r2.x * 128 + lane * 4);
    float4 h3 = ldrow4(H16 + (size_t)r3.x * 128 + lane * 4);
    float w0 = __int_as_float(r0.y), w1 = __int_as_float(r1.y);
    float w2 = __int_as_float(r2.y), w3 = __int_as_float(r3.y);
    acc.x = fmaf(w0, h0.x, acc.x); acc.y = fmaf(w0, h0.y, acc.y);
    acc.z = fmaf(w0, h0.z, acc.z); acc.w = fmaf(w0, h0.w, acc.w);
    acc.x = fmaf(w1, h1.x, acc.x); acc.y = fmaf(w1, h1.y, acc.y);
    acc.z = fmaf(w1, h1.z, acc.z); acc.w = fmaf(w1, h1.w, acc.w);
    acc.x = fmaf(w2, h2.x, acc.x); acc.y = fmaf(w2, h2.y, acc.y);
    acc.z = fmaf(w2, h2.z, acc.z); acc.w = fmaf(w2, h2.w, acc.w);
    acc.x = fmaf(w3, h3.x, acc.x); acc.y = fmaf(w3, h3.y, acc.y);
    acc.z = fmaf(w3, h3.z, acc.z); acc.w = fmaf(w3, h3.w, acc.w);
  }
  for (; k < end; ++k) {
    int2 r0 = rec[k];
    float w0 = __int_as_float(r0.y);
    float4 h0 = ldrow4(H16 + (size_t)r0.x * 128 + lane * 4);
    acc.x = fmaf(w0, h0.x, acc.x); acc.y = fmaf(w0, h0.y, acc.y);
    acc.z = fmaf(w0, h0.z, acc.z); acc.w = fmaf(w0, h0.w, acc.w);
  }

  float di = dinv[i];
  float ns = di * di;
  float4 hs = ldrow4(H16 + (size_t)i * 128 + lane * 4);
  float4 bb = *(const float4*)(bias + lane * 4);
  float4 v;
  v.x = fmaxf(fmaf(hs.x, ns, acc.x) + bb.x, 0.f);
  v.y = fmaxf(fmaf(hs.y, ns, acc.y) + bb.y, 0.f);
  v.z = fmaxf(fmaf(hs.z, ns, acc.z) + bb.z, 0.f);
  v.w = fmaxf(fmaf(hs.w, ns, acc.w) + bb.w, 0.f);
  st_nt_h4(B16 + (size_t)i * 128 + lane * 4, v.x, v.y, v.z, v.w);
}

// ---------------- layer-3 gather+pool: pooled[batch[i]] += A-row_i . P3 ----------------
// One thread per node; P3 is [N,8] fp32 = 3.2 MB (L2-resident random reads).

__global__ __launch_bounds__(THREADS) void k_gather_pool(const float* __restrict__ P3,
                                                         const int* __restrict__ rowptr,
                                                         const int2* __restrict__ rec,
                                                         const float* __restrict__ dinv,
                                                         const int* __restrict__ batch,
                                                         float* __restrict__ pooled,
                                                         int N) {
  int i = blockIdx.x * THREADS + threadIdx.x;
  if (i >= N) return;
  int beg = rowptr[i];
  int end = rowptr[i + 1];

  float4 a0 = make_float4(0.f, 0.f, 0.f, 0.f);
  float4 a1 = make_float4(0.f, 0.f, 0.f, 0.f);
  int k = beg;
  for (; k + 1 < end; k += 2) {
    int2 ra = rec[k], rb = rec[k + 1];
    float wa = __int_as_float(ra.y), wb = __int_as_float(rb.y);
    const float4* pa = (const float4*)(P3 + (size_t)ra.x * 8);
    const float4* pb = (const float4*)(P3 + (size_t)rb.x * 8);
    float4 pa0 = pa[0], pa1 = pa[1], pb0 = pb[0], pb1 = pb[1];
    a0.x = fmaf(wa, pa0.x, a0.x); a0.y = fmaf(wa, pa0.y, a0.y);
    a0.z = fmaf(wa, pa0.z, a0.z); a0.w = fmaf(wa, pa0.w, a0.w);
    a1.x = fmaf(wa, pa1.x, a1.x); a1.y = fmaf(wa, pa1.y, a1.y);
    a1.z = fmaf(wa, pa1.z, a1.z); a1.w = fmaf(wa, pa1.w, a1.w);
    a0.x = fmaf(wb, pb0.x, a0.x); a0.y = fmaf(wb, pb0.y, a0.y);
    a0.z = fmaf(wb, pb0.z, a0.z); a0.w = fmaf(wb, pb0.w, a0.w);
    a1.x = fmaf(wb, pb1.x, a1.x); a1.y = fmaf(wb, pb1.y, a1.y);
    a1.z = fmaf(wb, pb1.z, a1.z); a1.w = fmaf(wb, pb1.w, a1.w);
  }
  for (; k < end; ++k) {
    int2 ra = rec[k];
    float wa = __int_as_float(ra.y);
    const float4* pa = (const float4*)(P3 + (size_t)ra.x * 8);
    float4 pa0 = pa[0], pa1 = pa[1];
    a0.x = fmaf(wa, pa0.x, a0.x); a0.y = fmaf(wa, pa0.y, a0.y);
    a0.z = fmaf(wa, pa0.z, a0.z); a0.w = fmaf(wa, pa0.w, a0.w);
    a1.x = fmaf(wa, pa1.x, a1.x); a1.y = fmaf(wa, pa1.y, a1.y);
    a1.z = fmaf(wa, pa1.z, a1.z); a1.w = fmaf(wa, pa1.w, a1.w);
  }

  float dd = dinv[i];
  float ns = dd * dd;
  const float4* ps = (const float4*)(P3 + (size_t)i * 8);
  float4 s0 = ps[0], s1 = ps[1];
  a0.x = fmaf(ns, s0.x, a0.x); a0.y = fmaf(ns, s0.y, a0.y);
  a0.z = fmaf(ns, s0.z, a0.z); a0.w = fmaf(ns, s0.w, a0.w);
  a1.x = fmaf(ns, s1.x, a1.x); a1.y = fmaf(ns, s1.y, a1.y);
  a1.z = fmaf(ns, s1.z, a1.z); a1.w = fmaf(ns, s1.w, a1.w);

  float* o = pooled + (size_t)batch[i] * 8;
  atomicAdd(o + 0, a0.x); atomicAdd(o + 1, a0.y);
  atomicAdd(o + 2, a0.z); atomicAdd(o + 3, a0.w);
  atomicAdd(o + 4, a1.x); atomicAdd(o + 5, a1.y);
  atomicAdd(o + 6, a1.z); atomicAdd(o + 7, a1.w);
}

// ---------------- head: out[g,o] = pooled[g,o]/max(cnt,1) + bc[o] ----------------

__global__ __launch_bounds__(THREADS) void k_head(const float* __restrict__ pooled,
                                                  const float* __restrict__ cnts,
                                                  const float* __restrict__ bc,
                                                  float* __restrict__ out, int G) {
  int gid = blockIdx.x * THREADS + threadIdx.x;
  int g = gid >> 3;
  int o = gid & 7;
  if (g >= G) return;
  out[g * 8 + o] = pooled[g * 8 + o] / fmaxf(cnts[g], 1.0f) + bc[o];
}

// ---------------- launch ----------------

extern "C" void kernel_launch(void* const* d_in, const int* in_sizes, int n_in,
                              void* d_out, int out_size, void* d_ws, size_t ws_size,
                              hipStream_t stream) {
  const float* x     = (const float*)d_in[0];
  const int*   ei    = (const int*)d_in[1];
  const int*   batch = (const int*)d_in[3];
  const float* W1 = (const float*)d_in[4];
  const float* b1 = (const float*)d_in[5];
  const float* W2 = (const float*)d_in[6];
  const float* b2 = (const float*)d_in[7];
  const float* W3 = (const float*)d_in[8];
  const float* b3 = (const float*)d_in[9];
  const float* Wl = (const float*)d_in[10];
  const float* bl = (const float*)d_in[11];
  float* out = (float*)d_out;

  const int N = in_sizes[0] / 128;
  const int E = in_sizes[1] / 2;
  const int G = out_size / 8;
  const int* srcp = ei;
  const int* dstp = ei + E;

  char* ws = (char*)d_ws;
  __half* H16 = (__half*)ws;                       // [N,128] fp16 GEMM output
  __half* B16 = H16 + (size_t)N * 128;             // [N,128] fp16 activations
  float*  P3  = (float*)(B16 + (size_t)N * 128);   // [N,8] fp32 tail features
  // zeroed region: degi, cursor, cnts, pooled (contiguous)
  int*   degi   = (int*)(P3 + (size_t)N * 8);      // N
  int*   cursor = degi + N;                        // N
  float* cnts   = (float*)(cursor + N);            // G
  float* pooled = cnts + G;                        // G*8
  // non-zeroed scratch
  float* dinv    = pooled + (size_t)G * 8;         // N
  float* Wc      = dinv + N;                       // 1024
  float* bc      = Wc + 1024;                      // 8
  int*   rowptr  = (int*)(bc + 8);                 // N+1
  int*   bsum    = rowptr + N + 1;                 // scan partials (<=2048)
  int2*  rec     = (int2*)(bsum + 2048);           // E packed records

  const size_t zero_bytes = ((size_t)2 * N + G + (size_t)G * 8) * sizeof(float);
  (void)hipMemsetAsync(degi, 0, zero_bytes, stream);

  const int nbE = (E + THREADS - 1) / THREADS;
  const int nbN = (N + THREADS - 1) / THREADS;

  // ---- CSR build + tail-weight fold (once per call) ----
  k_deg<<<nbE, THREADS, 0, stream>>>(dstp, degi, E);
  k_cnt<<<nbN, THREADS, 0, stream>>>(batch, cnts, N);
  k_rsq<<<nbN, THREADS, 0, stream>>>(degi, dinv, N);
  k_scan1<<<nbN, THREADS, 0, stream>>>(degi, rowptr, bsum, N);
  k_scan2<<<1, 512, 0, stream>>>(bsum, nbN);
  k_scan3<<<nbN, THREADS, 0, stream>>>(rowptr, bsum, N, E);
  k_csr<<<nbE, THREADS, 0, stream>>>(srcp, dstp, rowptr, cursor, dinv, rec, E);
  k_wcomb<<<4, THREADS, 0, stream>>>(W3, Wl, b3, bl, Wc, bc);

  const int gemm_blocks = (N + 63) / 64;
  const int gat_blocks = (int)(((long long)N * 32 + THREADS - 1) / THREADS);

  // ---- layer 1 ----
  k_gemm128<float><<<gemm_blocks, THREADS, 0, stream>>>(x, W1, H16, N);
  k_gather<<<gat_blocks, THREADS, 0, stream>>>(H16, rowptr, rec, dinv, b1, B16, N);
  // ---- layer 2 ----
  k_gemm128<__half><<<gemm_blocks, THREADS, 0, stream>>>(B16, W2, H16, N);
  k_gather<<<gat_blocks, THREADS, 0, stream>>>(H16, rowptr, rec, dinv, b2, B16, N);
  // ---- layer 3 folded: P3 = B2 @ (W3@Wlin); gather+pool in 8-dim space ----
  k_gemm8<<<nbN, THREADS, 0, stream>>>(B16, Wc, P3, N);
  k_gather_pool<<<nbN, THREADS, 0, stream>>>(P3, rowptr, rec, dinv, batch, pooled, N);

  // ---- head ----
  k_head<<<(G * 8 + THREADS - 1) / THREADS, THREADS, 0, stream>>>(pooled, cnts, bc, out, G);
}

// Round 14
// 589.928 us; speedup vs baseline: 2.1803x; 1.1945x over previous
//
#include <hip/hip_runtime.h>
#include <hip/hip_fp16.h>

// GCN: 3x (h = X@W; agg = CSR-gather(norm_e * h[src]) + norm_self*h + b; relu)
// then mean-pool by graph id and a 128x8 linear head.
// R1: scatter->gather. R3: fp16 payload. R8: fp16 B + NT stores.
// R12: tail fold — out = mean_pool(A*(B2@(W3@Wlin))) + const; layer-3 gather
//      reads 16 B/edge from L2-fit P3[N,8]. 705 us.
// R13: k_gather_pool was latency-bound at 9% occupancy (1 thread/node = 391
//      blocks). Now 8 lanes/node (feature-per-lane): 3125 blocks, rec
//      broadcast within the 8-lane group, P3 row = one 32 B sector.

#define THREADS 256

// ---------------- degree(int) / counts / dinv ----------------

__global__ __launch_bounds__(THREADS) void k_deg(const int* __restrict__ dst,
                                                 int* __restrict__ degi, int E) {
  int e = blockIdx.x * THREADS + threadIdx.x;
  if (e < E) atomicAdd(&degi[dst[e]], 1);
}

__global__ __launch_bounds__(THREADS) void k_cnt(const int* __restrict__ batch,
                                                 float* __restrict__ cnts, int N) {
  int i = blockIdx.x * THREADS + threadIdx.x;
  if (i < N) atomicAdd(&cnts[batch[i]], 1.0f);
}

__global__ __launch_bounds__(THREADS) void k_rsq(const int* __restrict__ degi,
                                                 float* __restrict__ dinv, int N) {
  int i = blockIdx.x * THREADS + threadIdx.x;
  if (i < N) dinv[i] = rsqrtf((float)degi[i] + 1.0f);
}

// ---------------- exclusive scan (3 kernels) ----------------

__global__ __launch_bounds__(THREADS) void k_scan1(const int* __restrict__ degi,
                                                   int* __restrict__ rowptr,
                                                   int* __restrict__ bsum, int N) {
  __shared__ int s[THREADS];
  int i = blockIdx.x * THREADS + threadIdx.x;
  int v = (i < N) ? degi[i] : 0;
  s[threadIdx.x] = v;
  __syncthreads();
#pragma unroll
  for (int off = 1; off < THREADS; off <<= 1) {
    int t = (threadIdx.x >= off) ? s[threadIdx.x - off] : 0;
    __syncthreads();
    s[threadIdx.x] += t;
    __syncthreads();
  }
  if (i < N) rowptr[i] = s[threadIdx.x] - v;  // exclusive
  if (threadIdx.x == THREADS - 1) bsum[blockIdx.x] = s[THREADS - 1];
}

__global__ __launch_bounds__(512) void k_scan2(int* __restrict__ bsum, int nb) {
  __shared__ int s[512];
  int v = (threadIdx.x < nb) ? bsum[threadIdx.x] : 0;
  s[threadIdx.x] = v;
  __syncthreads();
#pragma unroll
  for (int off = 1; off < 512; off <<= 1) {
    int t = (threadIdx.x >= off) ? s[threadIdx.x - off] : 0;
    __syncthreads();
    s[threadIdx.x] += t;
    __syncthreads();
  }
  if (threadIdx.x < nb) bsum[threadIdx.x] = s[threadIdx.x] - v;  // exclusive
}

__global__ __launch_bounds__(THREADS) void k_scan3(int* __restrict__ rowptr,
                                                   const int* __restrict__ bsum,
                                                   int N, int E) {
  int i = blockIdx.x * THREADS + threadIdx.x;
  if (i < N) rowptr[i] += bsum[blockIdx.x];
  if (i == 0) rowptr[N] = E;
}

// ---------------- CSR placement: packed {src, w} records by dst ----------------

__global__ __launch_bounds__(THREADS) void k_csr(const int* __restrict__ src,
                                                 const int* __restrict__ dst,
                                                 const int* __restrict__ rowptr,
                                                 int* __restrict__ cursor,
                                                 const float* __restrict__ dinv,
                                                 int2* __restrict__ rec, int E) {
  int e = blockIdx.x * THREADS + threadIdx.x;
  if (e >= E) return;
  int s = src[e];
  int d = dst[e];
  int pos = atomicAdd(&cursor[d], 1);
  int idx = rowptr[d] + pos;
  float w = dinv[s] * dinv[d];
  rec[idx] = make_int2(s, __float_as_int(w));
}

// ---------------- combined tail weights: Wc = W3@Wlin, bc = b3@Wlin + blin ----------------

__global__ __launch_bounds__(THREADS) void k_wcomb(const float* __restrict__ W3,
                                                   const float* __restrict__ Wl,
                                                   const float* __restrict__ b3,
                                                   const float* __restrict__ bl,
                                                   float* __restrict__ Wc,
                                                   float* __restrict__ bc) {
  int idx = blockIdx.x * THREADS + threadIdx.x;
  if (idx < 1024) {
    int k = idx >> 3, o = idx & 7;
    float a = 0.f;
#pragma unroll 8
    for (int j = 0; j < 128; ++j) a = fmaf(W3[k * 128 + j], Wl[j * 8 + o], a);
    Wc[idx] = a;
  }
  if (idx < 8) {
    float a = bl[idx];
    for (int j = 0; j < 128; ++j) a = fmaf(b3[j], Wl[j * 8 + idx], a);
    bc[idx] = a;
  }
}

// ---------------- loaders / stores ----------------

__device__ inline float4 ldrow4(const float* __restrict__ p) {
  return *(const float4*)p;
}

__device__ inline float4 ldrow4(const __half* __restrict__ p) {
  float2 raw = *(const float2*)p;  // 4 halves
  const __half2* h = (const __half2*)&raw;
  float2 a = __half22float2(h[0]);
  float2 b = __half22float2(h[1]);
  return make_float4(a.x, a.y, b.x, b.y);
}

struct f8 { float v[8]; };

__device__ inline f8 ld_h8(const __half* __restrict__ p) {
  float4 raw = *(const float4*)p;  // 8 halves, 16 B
  const __half2* h = (const __half2*)&raw;
  float2 a = __half22float2(h[0]);
  float2 b = __half22float2(h[1]);
  float2 c = __half22float2(h[2]);
  float2 d = __half22float2(h[3]);
  f8 o;
  o.v[0] = a.x; o.v[1] = a.y; o.v[2] = b.x; o.v[3] = b.y;
  o.v[4] = c.x; o.v[5] = c.y; o.v[6] = d.x; o.v[7] = d.y;
  return o;
}

// fp16 pack + non-temporal 8 B store
__device__ inline void st_nt_h4(__half* __restrict__ p, float x, float y,
                                float z, float w) {
  union {
    __half2 h2[2];
    unsigned long long u;
  } cv;
  cv.h2[0] = __floats2half2_rn(x, y);
  cv.h2[1] = __floats2half2_rn(z, w);
  __builtin_nontemporal_store(cv.u, (unsigned long long*)p);
}

// ---------------- GEMM: H16[M,128] = fp16(X[M,128] @ W[128,128]) ----------------

template <typename T>
__global__ __launch_bounds__(THREADS) void k_gemm128(const T* __restrict__ X,
                                                     const float* __restrict__ W,
                                                     __half* __restrict__ H16, int M) {
  __shared__ float4 sW[128 * 32];  // [k][colgroup] : W[k][c0..c0+3]
  const int t = threadIdx.x;
#pragma unroll
  for (int i = 0; i < 16; ++i) sW[t + i * 256] = ((const float4*)W)[t + i * 256];
  __syncthreads();

  const int tx = t & 31;
  const int ty = t >> 5;
  const int r0 = blockIdx.x * 64 + ty * 8;

  const T* xp[8];
#pragma unroll
  for (int i = 0; i < 8; ++i) {
    int r = r0 + i;
    if (r >= M) r = M - 1;
    xp[i] = X + (size_t)r * 128;
  }

  float4 acc[8];
#pragma unroll
  for (int i = 0; i < 8; ++i) acc[i] = make_float4(0.f, 0.f, 0.f, 0.f);

#pragma unroll 2
  for (int k = 0; k < 128; k += 4) {
    float4 xv[8];
#pragma unroll
    for (int i = 0; i < 8; ++i) xv[i] = ldrow4(xp[i] + k);
#pragma unroll
    for (int kk = 0; kk < 4; ++kk) {
      float4 w = sW[(k + kk) * 32 + tx];
#pragma unroll
      for (int i = 0; i < 8; ++i) {
        float xs = (kk == 0) ? xv[i].x : (kk == 1) ? xv[i].y : (kk == 2) ? xv[i].z : xv[i].w;
        acc[i].x = fmaf(xs, w.x, acc[i].x);
        acc[i].y = fmaf(xs, w.y, acc[i].y);
        acc[i].z = fmaf(xs, w.z, acc[i].z);
        acc[i].w = fmaf(xs, w.w, acc[i].w);
      }
    }
  }

#pragma unroll
  for (int i = 0; i < 8; ++i) {
    int r = r0 + i;
    if (r < M)
      st_nt_h4(H16 + (size_t)r * 128 + tx * 4, acc[i].x, acc[i].y, acc[i].z, acc[i].w);
  }
}

// ---------------- small GEMM: P3[M,8] = fp32(B16[M,128] @ Wc[128,8]) ----------------

__global__ __launch_bounds__(THREADS) void k_gemm8(const __half* __restrict__ B16,
                                                   const float* __restrict__ Wc,
                                                   float* __restrict__ P3, int M) {
  __shared__ float sWc[1024];
#pragma unroll
  for (int i = 0; i < 4; ++i) sWc[threadIdx.x + i * 256] = Wc[threadIdx.x + i * 256];
  __syncthreads();

  int i = blockIdx.x * THREADS + threadIdx.x;
  if (i >= M) return;

  float acc[8];
#pragma unroll
  for (int o = 0; o < 8; ++o) acc[o] = 0.f;

  const __half* row = B16 + (size_t)i * 128;
#pragma unroll 4
  for (int k = 0; k < 128; k += 8) {
    f8 x = ld_h8(row + k);
#pragma unroll
    for (int u = 0; u < 8; ++u) {
      const float* wr = &sWc[(k + u) * 8];
#pragma unroll
      for (int o = 0; o < 8; ++o) acc[o] = fmaf(x.v[u], wr[o], acc[o]);
    }
  }
  float4* out = (float4*)(P3 + (size_t)i * 8);
  out[0] = make_float4(acc[0], acc[1], acc[2], acc[3]);
  out[1] = make_float4(acc[4], acc[5], acc[6], acc[7]);
}

// ---------------- gather: B16[i] = fp16(sum_in w*H16[src] + dinv_i^2*H16[i] + bias) ----------------
// R8 proven shape: 32 lanes per dst node, 8 B per lane; unroll 4; NT store.

__global__ __launch_bounds__(THREADS) void k_gather(const __half* __restrict__ H16,
                                                    const int* __restrict__ rowptr,
                                                    const int2* __restrict__ rec,
                                                    const float* __restrict__ dinv,
                                                    const float* __restrict__ bias,
                                                    __half* __restrict__ B16, int N) {
  int gid = blockIdx.x * THREADS + threadIdx.x;
  int i = gid >> 5;
  int lane = gid & 31;
  if (i >= N) return;
  int beg = rowptr[i];
  int end = rowptr[i + 1];

  float4 acc = make_float4(0.f, 0.f, 0.f, 0.f);
  int k = beg;
  for (; k + 3 < end; k += 4) {
    int2 r0 = rec[k],     r1 = rec[k + 1];
    int2 r2 = rec[k + 2], r3 = rec[k + 3];
    float4 h0 = ldrow4(H16 + (size_t)r0.x * 128 + lane * 4);
    float4 h1 = ldrow4(H16 + (size_t)r1.x * 128 + lane * 4);
    float4 h2 = ldrow4(H16 + (size_t)r2.x * 128 + lane * 4);
    float4 h3 = ldrow4(H16 + (size_t)r3.x * 128 + lane * 4);
    float w0 = __int_as_float(r0.y), w1 = __int_as_float(r1.y);
    float w2 = __int_as_float(r2.y), w3 = __int_as_float(r3.y);
    acc.x = fmaf(w0, h0.x, acc.x); acc.y = fmaf(w0, h0.y, acc.y);
    acc.z = fmaf(w0, h0.z, acc.z); acc.w = fmaf(w0, h0.w, acc.w);
    acc.x = fmaf(w1, h1.x, acc.x); acc.y = fmaf(w1, h1.y, acc.y);
    acc.z = fmaf(w1, h1.z, acc.z); acc.w = fmaf(w1, h1.w, acc.w);
    acc.x = fmaf(w2, h2.x, acc.x); acc.y = fmaf(w2, h2.y, acc.y);
    acc.z = fmaf(w2, h2.z, acc.z); acc.w = fmaf(w2, h2.w, acc.w);
    acc.x = fmaf(w3, h3.x, acc.x); acc.y = fmaf(w3, h3.y, acc.y);
    acc.z = fmaf(w3, h3.z, acc.z); acc.w = fmaf(w3, h3.w, acc.w);
  }
  for (; k < end; ++k) {
    int2 r0 = rec[k];
    float w0 = __int_as_float(r0.y);
    float4 h0 = ldrow4(H16 + (size_t)r0.x * 128 + lane * 4);
    acc.x = fmaf(w0, h0.x, acc.x); acc.y = fmaf(w0, h0.y, acc.y);
    acc.z = fmaf(w0, h0.z, acc.z); acc.w = fmaf(w0, h0.w, acc.w);
  }

  float di = dinv[i];
  float ns = di * di;
  float4 hs = ldrow4(H16 + (size_t)i * 128 + lane * 4);
  float4 bb = *(const float4*)(bias + lane * 4);
  float4 v;
  v.x = fmaxf(fmaf(hs.x, ns, acc.x) + bb.x, 0.f);
  v.y = fmaxf(fmaf(hs.y, ns, acc.y) + bb.y, 0.f);
  v.z = fmaxf(fmaf(hs.z, ns, acc.z) + bb.z, 0.f);
  v.w = fmaxf(fmaf(hs.w, ns, acc.w) + bb.w, 0.f);
  st_nt_h4(B16 + (size_t)i * 128 + lane * 4, v.x, v.y, v.z, v.w);
}

// ---------------- layer-3 gather+pool: pooled[batch[i], l] += (A-row_i . P3)[l] ----------------
// 8 lanes per node, one feature per lane. rec reads broadcast within the
// 8-lane group; P3 row = one 32 B sector. 800K threads -> ~12 blocks/CU.

__global__ __launch_bounds__(THREADS) void k_gather_pool(const float* __restrict__ P3,
                                                         const int* __restrict__ rowptr,
                                                         const int2* __restrict__ rec,
                                                         const float* __restrict__ dinv,
                                                         const int* __restrict__ batch,
                                                         float* __restrict__ pooled,
                                                         int N) {
  int gid = blockIdx.x * THREADS + threadIdx.x;
  int i = gid >> 3;
  int lane = gid & 7;
  if (i >= N) return;
  int beg = rowptr[i];
  int end = rowptr[i + 1];

  float acc = 0.f;
  int k = beg;
  for (; k + 1 < end; k += 2) {
    int2 ra = rec[k], rb = rec[k + 1];
    float pa = P3[(size_t)ra.x * 8 + lane];
    float pb = P3[(size_t)rb.x * 8 + lane];
    acc = fmaf(__int_as_float(ra.y), pa, acc);
    acc = fmaf(__int_as_float(rb.y), pb, acc);
  }
  if (k < end) {
    int2 ra = rec[k];
    acc = fmaf(__int_as_float(ra.y), P3[(size_t)ra.x * 8 + lane], acc);
  }

  float dd = dinv[i];
  acc = fmaf(dd * dd, P3[(size_t)i * 8 + lane], acc);

  atomicAdd(&pooled[(size_t)batch[i] * 8 + lane], acc);
}

// ---------------- head: out[g,o] = pooled[g,o]/max(cnt,1) + bc[o] ----------------

__global__ __launch_bounds__(THREADS) void k_head(const float* __restrict__ pooled,
                                                  const float* __restrict__ cnts,
                                                  const float* __restrict__ bc,
                                                  float* __restrict__ out, int G) {
  int gid = blockIdx.x * THREADS + threadIdx.x;
  int g = gid >> 3;
  int o = gid & 7;
  if (g >= G) return;
  out[g * 8 + o] = pooled[g * 8 + o] / fmaxf(cnts[g], 1.0f) + bc[o];
}

// ---------------- launch ----------------

extern "C" void kernel_launch(void* const* d_in, const int* in_sizes, int n_in,
                              void* d_out, int out_size, void* d_ws, size_t ws_size,
                              hipStream_t stream) {
  const float* x     = (const float*)d_in[0];
  const int*   ei    = (const int*)d_in[1];
  const int*   batch = (const int*)d_in[3];
  const float* W1 = (const float*)d_in[4];
  const float* b1 = (const float*)d_in[5];
  const float* W2 = (const float*)d_in[6];
  const float* b2 = (const float*)d_in[7];
  const float* W3 = (const float*)d_in[8];
  const float* b3 = (const float*)d_in[9];
  const float* Wl = (const float*)d_in[10];
  const float* bl = (const float*)d_in[11];
  float* out = (float*)d_out;

  const int N = in_sizes[0] / 128;
  const int E = in_sizes[1] / 2;
  const int G = out_size / 8;
  const int* srcp = ei;
  const int* dstp = ei + E;

  char* ws = (char*)d_ws;
  __half* H16 = (__half*)ws;                       // [N,128] fp16 GEMM output
  __half* B16 = H16 + (size_t)N * 128;             // [N,128] fp16 activations
  float*  P3  = (float*)(B16 + (size_t)N * 128);   // [N,8] fp32 tail features
  // zeroed region: degi, cursor, cnts, pooled (contiguous)
  int*   degi   = (int*)(P3 + (size_t)N * 8);      // N
  int*   cursor = degi + N;                        // N
  float* cnts   = (float*)(cursor + N);            // G
  float* pooled = cnts + G;                        // G*8
  // non-zeroed scratch
  float* dinv    = pooled + (size_t)G * 8;         // N
  float* Wc      = dinv + N;                       // 1024
  float* bc      = Wc + 1024;                      // 8
  int*   rowptr  = (int*)(bc + 8);                 // N+1
  int*   bsum    = rowptr + N + 1;                 // scan partials (<=2048)
  int2*  rec     = (int2*)(bsum + 2048);           // E packed records

  const size_t zero_bytes = ((size_t)2 * N + G + (size_t)G * 8) * sizeof(float);
  (void)hipMemsetAsync(degi, 0, zero_bytes, stream);

  const int nbE = (E + THREADS - 1) / THREADS;
  const int nbN = (N + THREADS - 1) / THREADS;

  // ---- CSR build + tail-weight fold (once per call) ----
  k_deg<<<nbE, THREADS, 0, stream>>>(dstp, degi, E);
  k_cnt<<<nbN, THREADS, 0, stream>>>(batch, cnts, N);
  k_rsq<<<nbN, THREADS, 0, stream>>>(degi, dinv, N);
  k_scan1<<<nbN, THREADS, 0, stream>>>(degi, rowptr, bsum, N);
  k_scan2<<<1, 512, 0, stream>>>(bsum, nbN);
  k_scan3<<<nbN, THREADS, 0, stream>>>(rowptr, bsum, N, E);
  k_csr<<<nbE, THREADS, 0, stream>>>(srcp, dstp, rowptr, cursor, dinv, rec, E);
  k_wcomb<<<4, THREADS, 0, stream>>>(W3, Wl, b3, bl, Wc, bc);

  const int gemm_blocks = (N + 63) / 64;
  const int gat_blocks = (int)(((long long)N * 32 + THREADS - 1) / THREADS);
  const int gp_blocks = (int)(((long long)N * 8 + THREADS - 1) / THREADS);

  // ---- layer 1 ----
  k_gemm128<float><<<gemm_blocks, THREADS, 0, stream>>>(x, W1, H16, N);
  k_gather<<<gat_blocks, THREADS, 0, stream>>>(H16, rowptr, rec, dinv, b1, B16, N);
  // ---- layer 2 ----
  k_gemm128<__half><<<gemm_blocks, THREADS, 0, stream>>>(B16, W2, H16, N);
  k_gather<<<gat_blocks, THREADS, 0, stream>>>(H16, rowptr, rec, dinv, b2, B16, N);
  // ---- layer 3 folded: P3 = B2 @ (W3@Wlin); gather+pool in 8-dim space ----
  k_gemm8<<<nbN, THREADS, 0, stream>>>(B16, Wc, P3, N);
  k_gather_pool<<<gp_blocks, THREADS, 0, stream>>>(P3, rowptr, rec, dinv, batch, pooled, N);

  // ---- head ----
  k_head<<<(G * 8 + THREADS - 1) / THREADS, THREADS, 0, stream>>>(pooled, cnts, bc, out, G);
}

// Round 15
// 510.238 us; speedup vs baseline: 2.5209x; 1.1562x over previous
//
#include <hip/hip_runtime.h>
#include <hip/hip_fp16.h>

// GCN: 3x (h = X@W; agg = CSR-gather(norm_e * h[src]) + norm_self*h + b; relu)
// then mean-pool by graph id and a 128x8 linear head.
// R1: scatter->gather. R3: fp16 payload. R8: fp16 B + NT stores.
// R12: tail fold (layer-3 gather in 8-dim space). R13: 8-lane gather_pool. 590 us.
// R14: build phase now 40% of runtime.
//   (a) k_cnt was same-address atomic serialization (batch sorted, 97 us) ->
//       binary-search counts, no atomics.
//   (b) k_csr rec scatter: NT store (8B random scatter write-amped 9x).

#define THREADS 256

// ---------------- degree(int) / dinv ----------------

__global__ __launch_bounds__(THREADS) void k_deg(const int* __restrict__ dst,
                                                 int* __restrict__ degi, int E) {
  int e = blockIdx.x * THREADS + threadIdx.x;
  if (e < E) atomicAdd(&degi[dst[e]], 1);
}

// counts via binary search over sorted batch (no atomics)
__global__ __launch_bounds__(THREADS) void k_cntbs(const int* __restrict__ batch,
                                                   float* __restrict__ cnts,
                                                   int N, int G) {
  int g = blockIdx.x * THREADS + threadIdx.x;
  if (g >= G) return;
  int lo = 0, hi = N;
  while (lo < hi) {
    int mid = (lo + hi) >> 1;
    if (batch[mid] < g) lo = mid + 1; else hi = mid;
  }
  int lb0 = lo;
  lo = 0; hi = N;
  while (lo < hi) {
    int mid = (lo + hi) >> 1;
    if (batch[mid] < g + 1) lo = mid + 1; else hi = mid;
  }
  cnts[g] = (float)(lo - lb0);
}

__global__ __launch_bounds__(THREADS) void k_rsq(const int* __restrict__ degi,
                                                 float* __restrict__ dinv, int N) {
  int i = blockIdx.x * THREADS + threadIdx.x;
  if (i < N) dinv[i] = rsqrtf((float)degi[i] + 1.0f);
}

// ---------------- exclusive scan (3 kernels) ----------------

__global__ __launch_bounds__(THREADS) void k_scan1(const int* __restrict__ degi,
                                                   int* __restrict__ rowptr,
                                                   int* __restrict__ bsum, int N) {
  __shared__ int s[THREADS];
  int i = blockIdx.x * THREADS + threadIdx.x;
  int v = (i < N) ? degi[i] : 0;
  s[threadIdx.x] = v;
  __syncthreads();
#pragma unroll
  for (int off = 1; off < THREADS; off <<= 1) {
    int t = (threadIdx.x >= off) ? s[threadIdx.x - off] : 0;
    __syncthreads();
    s[threadIdx.x] += t;
    __syncthreads();
  }
  if (i < N) rowptr[i] = s[threadIdx.x] - v;  // exclusive
  if (threadIdx.x == THREADS - 1) bsum[blockIdx.x] = s[THREADS - 1];
}

__global__ __launch_bounds__(512) void k_scan2(int* __restrict__ bsum, int nb) {
  __shared__ int s[512];
  int v = (threadIdx.x < nb) ? bsum[threadIdx.x] : 0;
  s[threadIdx.x] = v;
  __syncthreads();
#pragma unroll
  for (int off = 1; off < 512; off <<= 1) {
    int t = (threadIdx.x >= off) ? s[threadIdx.x - off] : 0;
    __syncthreads();
    s[threadIdx.x] += t;
    __syncthreads();
  }
  if (threadIdx.x < nb) bsum[threadIdx.x] = s[threadIdx.x] - v;  // exclusive
}

__global__ __launch_bounds__(THREADS) void k_scan3(int* __restrict__ rowptr,
                                                   const int* __restrict__ bsum,
                                                   int N, int E) {
  int i = blockIdx.x * THREADS + threadIdx.x;
  if (i < N) rowptr[i] += bsum[blockIdx.x];
  if (i == 0) rowptr[N] = E;
}

// ---------------- CSR placement: packed {src, w} records by dst (NT store) ----------------

__global__ __launch_bounds__(THREADS) void k_csr(const int* __restrict__ src,
                                                 const int* __restrict__ dst,
                                                 const int* __restrict__ rowptr,
                                                 int* __restrict__ cursor,
                                                 const float* __restrict__ dinv,
                                                 int2* __restrict__ rec, int E) {
  int e = blockIdx.x * THREADS + threadIdx.x;
  if (e >= E) return;
  int s = src[e];
  int d = dst[e];
  int pos = atomicAdd(&cursor[d], 1);
  int idx = rowptr[d] + pos;
  float w = dinv[s] * dinv[d];
  union {
    int2 v;
    unsigned long long u;
  } cv;
  cv.v = make_int2(s, __float_as_int(w));
  __builtin_nontemporal_store(cv.u, (unsigned long long*)&rec[idx]);
}

// ---------------- combined tail weights: Wc = W3@Wlin, bc = b3@Wlin + blin ----------------

__global__ __launch_bounds__(THREADS) void k_wcomb(const float* __restrict__ W3,
                                                   const float* __restrict__ Wl,
                                                   const float* __restrict__ b3,
                                                   const float* __restrict__ bl,
                                                   float* __restrict__ Wc,
                                                   float* __restrict__ bc) {
  int idx = blockIdx.x * THREADS + threadIdx.x;
  if (idx < 1024) {
    int k = idx >> 3, o = idx & 7;
    float a = 0.f;
#pragma unroll 8
    for (int j = 0; j < 128; ++j) a = fmaf(W3[k * 128 + j], Wl[j * 8 + o], a);
    Wc[idx] = a;
  }
  if (idx < 8) {
    float a = bl[idx];
    for (int j = 0; j < 128; ++j) a = fmaf(b3[j], Wl[j * 8 + idx], a);
    bc[idx] = a;
  }
}

// ---------------- loaders / stores ----------------

__device__ inline float4 ldrow4(const float* __restrict__ p) {
  return *(const float4*)p;
}

__device__ inline float4 ldrow4(const __half* __restrict__ p) {
  float2 raw = *(const float2*)p;  // 4 halves
  const __half2* h = (const __half2*)&raw;
  float2 a = __half22float2(h[0]);
  float2 b = __half22float2(h[1]);
  return make_float4(a.x, a.y, b.x, b.y);
}

struct f8 { float v[8]; };

__device__ inline f8 ld_h8(const __half* __restrict__ p) {
  float4 raw = *(const float4*)p;  // 8 halves, 16 B
  const __half2* h = (const __half2*)&raw;
  float2 a = __half22float2(h[0]);
  float2 b = __half22float2(h[1]);
  float2 c = __half22float2(h[2]);
  float2 d = __half22float2(h[3]);
  f8 o;
  o.v[0] = a.x; o.v[1] = a.y; o.v[2] = b.x; o.v[3] = b.y;
  o.v[4] = c.x; o.v[5] = c.y; o.v[6] = d.x; o.v[7] = d.y;
  return o;
}

// fp16 pack + non-temporal 8 B store
__device__ inline void st_nt_h4(__half* __restrict__ p, float x, float y,
                                float z, float w) {
  union {
    __half2 h2[2];
    unsigned long long u;
  } cv;
  cv.h2[0] = __floats2half2_rn(x, y);
  cv.h2[1] = __floats2half2_rn(z, w);
  __builtin_nontemporal_store(cv.u, (unsigned long long*)p);
}

// ---------------- GEMM: H16[M,128] = fp16(X[M,128] @ W[128,128]) ----------------

template <typename T>
__global__ __launch_bounds__(THREADS) void k_gemm128(const T* __restrict__ X,
                                                     const float* __restrict__ W,
                                                     __half* __restrict__ H16, int M) {
  __shared__ float4 sW[128 * 32];  // [k][colgroup] : W[k][c0..c0+3]
  const int t = threadIdx.x;
#pragma unroll
  for (int i = 0; i < 16; ++i) sW[t + i * 256] = ((const float4*)W)[t + i * 256];
  __syncthreads();

  const int tx = t & 31;
  const int ty = t >> 5;
  const int r0 = blockIdx.x * 64 + ty * 8;

  const T* xp[8];
#pragma unroll
  for (int i = 0; i < 8; ++i) {
    int r = r0 + i;
    if (r >= M) r = M - 1;
    xp[i] = X + (size_t)r * 128;
  }

  float4 acc[8];
#pragma unroll
  for (int i = 0; i < 8; ++i) acc[i] = make_float4(0.f, 0.f, 0.f, 0.f);

#pragma unroll 2
  for (int k = 0; k < 128; k += 4) {
    float4 xv[8];
#pragma unroll
    for (int i = 0; i < 8; ++i) xv[i] = ldrow4(xp[i] + k);
#pragma unroll
    for (int kk = 0; kk < 4; ++kk) {
      float4 w = sW[(k + kk) * 32 + tx];
#pragma unroll
      for (int i = 0; i < 8; ++i) {
        float xs = (kk == 0) ? xv[i].x : (kk == 1) ? xv[i].y : (kk == 2) ? xv[i].z : xv[i].w;
        acc[i].x = fmaf(xs, w.x, acc[i].x);
        acc[i].y = fmaf(xs, w.y, acc[i].y);
        acc[i].z = fmaf(xs, w.z, acc[i].z);
        acc[i].w = fmaf(xs, w.w, acc[i].w);
      }
    }
  }

#pragma unroll
  for (int i = 0; i < 8; ++i) {
    int r = r0 + i;
    if (r < M)
      st_nt_h4(H16 + (size_t)r * 128 + tx * 4, acc[i].x, acc[i].y, acc[i].z, acc[i].w);
  }
}

// ---------------- small GEMM: P3[M,8] = fp32(B16[M,128] @ Wc[128,8]) ----------------

__global__ __launch_bounds__(THREADS) void k_gemm8(const __half* __restrict__ B16,
                                                   const float* __restrict__ Wc,
                                                   float* __restrict__ P3, int M) {
  __shared__ float sWc[1024];
#pragma unroll
  for (int i = 0; i < 4; ++i) sWc[threadIdx.x + i * 256] = Wc[threadIdx.x + i * 256];
  __syncthreads();

  int i = blockIdx.x * THREADS + threadIdx.x;
  if (i >= M) return;

  float acc[8];
#pragma unroll
  for (int o = 0; o < 8; ++o) acc[o] = 0.f;

  const __half* row = B16 + (size_t)i * 128;
#pragma unroll 4
  for (int k = 0; k < 128; k += 8) {
    f8 x = ld_h8(row + k);
#pragma unroll
    for (int u = 0; u < 8; ++u) {
      const float* wr = &sWc[(k + u) * 8];
#pragma unroll
      for (int o = 0; o < 8; ++o) acc[o] = fmaf(x.v[u], wr[o], acc[o]);
    }
  }
  float4* out = (float4*)(P3 + (size_t)i * 8);
  out[0] = make_float4(acc[0], acc[1], acc[2], acc[3]);
  out[1] = make_float4(acc[4], acc[5], acc[6], acc[7]);
}

// ---------------- gather: B16[i] = fp16(sum_in w*H16[src] + dinv_i^2*H16[i] + bias) ----------------
// R8 proven shape: 32 lanes per dst node, 8 B per lane; unroll 4; NT store.

__global__ __launch_bounds__(THREADS) void k_gather(const __half* __restrict__ H16,
                                                    const int* __restrict__ rowptr,
                                                    const int2* __restrict__ rec,
                                                    const float* __restrict__ dinv,
                                                    const float* __restrict__ bias,
                                                    __half* __restrict__ B16, int N) {
  int gid = blockIdx.x * THREADS + threadIdx.x;
  int i = gid >> 5;
  int lane = gid & 31;
  if (i >= N) return;
  int beg = rowptr[i];
  int end = rowptr[i + 1];

  float4 acc = make_float4(0.f, 0.f, 0.f, 0.f);
  int k = beg;
  for (; k + 3 < end; k += 4) {
    int2 r0 = rec[k],     r1 = rec[k + 1];
    int2 r2 = rec[k + 2], r3 = rec[k + 3];
    float4 h0 = ldrow4(H16 + (size_t)r0.x * 128 + lane * 4);
    float4 h1 = ldrow4(H16 + (size_t)r1.x * 128 + lane * 4);
    float4 h2 = ldrow4(H16 + (size_t)r2.x * 128 + lane * 4);
    float4 h3 = ldrow4(H16 + (size_t)r3.x * 128 + lane * 4);
    float w0 = __int_as_float(r0.y), w1 = __int_as_float(r1.y);
    float w2 = __int_as_float(r2.y), w3 = __int_as_float(r3.y);
    acc.x = fmaf(w0, h0.x, acc.x); acc.y = fmaf(w0, h0.y, acc.y);
    acc.z = fmaf(w0, h0.z, acc.z); acc.w = fmaf(w0, h0.w, acc.w);
    acc.x = fmaf(w1, h1.x, acc.x); acc.y = fmaf(w1, h1.y, acc.y);
    acc.z = fmaf(w1, h1.z, acc.z); acc.w = fmaf(w1, h1.w, acc.w);
    acc.x = fmaf(w2, h2.x, acc.x); acc.y = fmaf(w2, h2.y, acc.y);
    acc.z = fmaf(w2, h2.z, acc.z); acc.w = fmaf(w2, h2.w, acc.w);
    acc.x = fmaf(w3, h3.x, acc.x); acc.y = fmaf(w3, h3.y, acc.y);
    acc.z = fmaf(w3, h3.z, acc.z); acc.w = fmaf(w3, h3.w, acc.w);
  }
  for (; k < end; ++k) {
    int2 r0 = rec[k];
    float w0 = __int_as_float(r0.y);
    float4 h0 = ldrow4(H16 + (size_t)r0.x * 128 + lane * 4);
    acc.x = fmaf(w0, h0.x, acc.x); acc.y = fmaf(w0, h0.y, acc.y);
    acc.z = fmaf(w0, h0.z, acc.z); acc.w = fmaf(w0, h0.w, acc.w);
  }

  float di = dinv[i];
  float ns = di * di;
  float4 hs = ldrow4(H16 + (size_t)i * 128 + lane * 4);
  float4 bb = *(const float4*)(bias + lane * 4);
  float4 v;
  v.x = fmaxf(fmaf(hs.x, ns, acc.x) + bb.x, 0.f);
  v.y = fmaxf(fmaf(hs.y, ns, acc.y) + bb.y, 0.f);
  v.z = fmaxf(fmaf(hs.z, ns, acc.z) + bb.z, 0.f);
  v.w = fmaxf(fmaf(hs.w, ns, acc.w) + bb.w, 0.f);
  st_nt_h4(B16 + (size_t)i * 128 + lane * 4, v.x, v.y, v.z, v.w);
}

// ---------------- layer-3 gather+pool: pooled[batch[i], l] += (A-row_i . P3)[l] ----------------

__global__ __launch_bounds__(THREADS) void k_gather_pool(const float* __restrict__ P3,
                                                         const int* __restrict__ rowptr,
                                                         const int2* __restrict__ rec,
                                                         const float* __restrict__ dinv,
                                                         const int* __restrict__ batch,
                                                         float* __restrict__ pooled,
                                                         int N) {
  int gid = blockIdx.x * THREADS + threadIdx.x;
  int i = gid >> 3;
  int lane = gid & 7;
  if (i >= N) return;
  int beg = rowptr[i];
  int end = rowptr[i + 1];

  float acc = 0.f;
  int k = beg;
  for (; k + 1 < end; k += 2) {
    int2 ra = rec[k], rb = rec[k + 1];
    float pa = P3[(size_t)ra.x * 8 + lane];
    float pb = P3[(size_t)rb.x * 8 + lane];
    acc = fmaf(__int_as_float(ra.y), pa, acc);
    acc = fmaf(__int_as_float(rb.y), pb, acc);
  }
  if (k < end) {
    int2 ra = rec[k];
    acc = fmaf(__int_as_float(ra.y), P3[(size_t)ra.x * 8 + lane], acc);
  }

  float dd = dinv[i];
  acc = fmaf(dd * dd, P3[(size_t)i * 8 + lane], acc);

  atomicAdd(&pooled[(size_t)batch[i] * 8 + lane], acc);
}

// ---------------- head: out[g,o] = pooled[g,o]/max(cnt,1) + bc[o] ----------------

__global__ __launch_bounds__(THREADS) void k_head(const float* __restrict__ pooled,
                                                  const float* __restrict__ cnts,
                                                  const float* __restrict__ bc,
                                                  float* __restrict__ out, int G) {
  int gid = blockIdx.x * THREADS + threadIdx.x;
  int g = gid >> 3;
  int o = gid & 7;
  if (g >= G) return;
  out[g * 8 + o] = pooled[g * 8 + o] / fmaxf(cnts[g], 1.0f) + bc[o];
}

// ---------------- launch ----------------

extern "C" void kernel_launch(void* const* d_in, const int* in_sizes, int n_in,
                              void* d_out, int out_size, void* d_ws, size_t ws_size,
                              hipStream_t stream) {
  const float* x     = (const float*)d_in[0];
  const int*   ei    = (const int*)d_in[1];
  const int*   batch = (const int*)d_in[3];
  const float* W1 = (const float*)d_in[4];
  const float* b1 = (const float*)d_in[5];
  const float* W2 = (const float*)d_in[6];
  const float* b2 = (const float*)d_in[7];
  const float* W3 = (const float*)d_in[8];
  const float* b3 = (const float*)d_in[9];
  const float* Wl = (const float*)d_in[10];
  const float* bl = (const float*)d_in[11];
  float* out = (float*)d_out;

  const int N = in_sizes[0] / 128;
  const int E = in_sizes[1] / 2;
  const int G = out_size / 8;
  const int* srcp = ei;
  const int* dstp = ei + E;

  char* ws = (char*)d_ws;
  __half* H16 = (__half*)ws;                       // [N,128] fp16 GEMM output
  __half* B16 = H16 + (size_t)N * 128;             // [N,128] fp16 activations
  float*  P3  = (float*)(B16 + (size_t)N * 128);   // [N,8] fp32 tail features
  // zeroed region: degi, cursor, pooled (contiguous)
  int*   degi   = (int*)(P3 + (size_t)N * 8);      // N
  int*   cursor = degi + N;                        // N
  float* pooled = (float*)(cursor + N);            // G*8
  // non-zeroed scratch
  float* cnts    = pooled + (size_t)G * 8;         // G (binary-search fill)
  float* dinv    = cnts + G;                       // N
  float* Wc      = dinv + N;                       // 1024
  float* bc      = Wc + 1024;                      // 8
  int*   rowptr  = (int*)(bc + 8);                 // N+1
  int*   bsum    = rowptr + N + 1;                 // scan partials (<=2048)
  int2*  rec     = (int2*)(bsum + 2048);           // E packed records

  const size_t zero_bytes = ((size_t)2 * N + (size_t)G * 8) * sizeof(float);
  (void)hipMemsetAsync(degi, 0, zero_bytes, stream);

  const int nbE = (E + THREADS - 1) / THREADS;
  const int nbN = (N + THREADS - 1) / THREADS;

  // ---- CSR build + tail-weight fold (once per call) ----
  k_deg<<<nbE, THREADS, 0, stream>>>(dstp, degi, E);
  k_cntbs<<<(G + THREADS - 1) / THREADS, THREADS, 0, stream>>>(batch, cnts, N, G);
  k_rsq<<<nbN, THREADS, 0, stream>>>(degi, dinv, N);
  k_scan1<<<nbN, THREADS, 0, stream>>>(degi, rowptr, bsum, N);
  k_scan2<<<1, 512, 0, stream>>>(bsum, nbN);
  k_scan3<<<nbN, THREADS, 0, stream>>>(rowptr, bsum, N, E);
  k_csr<<<nbE, THREADS, 0, stream>>>(srcp, dstp, rowptr, cursor, dinv, rec, E);
  k_wcomb<<<4, THREADS, 0, stream>>>(W3, Wl, b3, bl, Wc, bc);

  const int gemm_blocks = (N + 63) / 64;
  const int gat_blocks = (int)(((long long)N * 32 + THREADS - 1) / THREADS);
  const int gp_blocks = (int)(((long long)N * 8 + THREADS - 1) / THREADS);

  // ---- layer 1 ----
  k_gemm128<float><<<gemm_blocks, THREADS, 0, stream>>>(x, W1, H16, N);
  k_gather<<<gat_blocks, THREADS, 0, stream>>>(H16, rowptr, rec, dinv, b1, B16, N);
  // ---- layer 2 ----
  k_gemm128<__half><<<gemm_blocks, THREADS, 0, stream>>>(B16, W2, H16, N);
  k_gather<<<gat_blocks, THREADS, 0, stream>>>(H16, rowptr, rec, dinv, b2, B16, N);
  // ---- layer 3 folded: P3 = B2 @ (W3@Wlin); gather+pool in 8-dim space ----
  k_gemm8<<<nbN, THREADS, 0, stream>>>(B16, Wc, P3, N);
  k_gather_pool<<<gp_blocks, THREADS, 0, stream>>>(P3, rowptr, rec, dinv, batch, pooled, N);

  // ---- head ----
  k_head<<<(G * 8 + THREADS - 1) / THREADS, THREADS, 0, stream>>>(pooled, cnts, bc, out, G);
}